// Round 1
// baseline (1334.807 us; speedup 1.0000x reference)
//
#include <hip/hip_runtime.h>

#define NROWS 65536
#define DDIM  512
#define EDIM  256
#define TDIM  128
#define KTOT  896      // D+E+T
#define MT    32       // rows per qproj block
#define APAD  904      // 896 + 8 bf16 pad -> 452 dwords stride == 4 mod 32 (2-way, free)

using bf16x8 = __attribute__((ext_vector_type(8))) short;
using f32x4  = __attribute__((ext_vector_type(4))) float;

static __device__ __forceinline__ unsigned short f2bf(float f) {
    unsigned int u = __float_as_uint(f);
    return (unsigned short)((u + 0x7fffu + ((u >> 16) & 1u)) >> 16);  // RNE
}
static __device__ __forceinline__ float clampf(float x, float lo, float hi) {
    return fminf(fmaxf(x, lo), hi);
}
static __device__ __forceinline__ float wred_sum(float v) {
    #pragma unroll
    for (int m = 32; m > 0; m >>= 1) v += __shfl_xor(v, m, 64);
    return v;
}
static __device__ __forceinline__ float tanh_fast(float x) {
    x = clampf(x, -15.f, 15.f);           // guard exp overflow; tanh saturated anyway
    float e = __expf(2.f * x);
    return (e - 1.f) / (e + 1.f);
}

// ---------------- kernel 0: Wq fp32 -> bf16 (458752 elems = 114688 float4) --------
__global__ void k_conv_wq(const float* __restrict__ wq, unsigned short* __restrict__ o) {
    int i = blockIdx.x * 256 + threadIdx.x;           // grid sized exactly: 448*256
    float4 v = ((const float4*)wq)[i];
    ushort4 r;
    r.x = f2bf(v.x); r.y = f2bf(v.y); r.z = f2bf(v.z); r.w = f2bf(v.w);
    ((ushort4*)o)[i] = r;
}

// ---------------- kernel 1: query = tanh(LN(concat(raw,edge,time) @ Wq^T + bq)) ----
// 256 thr = 4 waves; block does 32 rows x all 512 cols. Query written into d_out (fp32).
__global__ __launch_bounds__(256, 2) void k_qproj(
    const float* __restrict__ raw, const float* __restrict__ edge,
    const float* __restrict__ timee, const unsigned short* __restrict__ wqb,
    const float* __restrict__ bq, const float* __restrict__ gamma,
    const float* __restrict__ beta, float* __restrict__ qout)
{
    __shared__ union {
        unsigned short a[MT * APAD];   // 57856 B  (A-stage, bf16)
        float          c[MT * DDIM];   // 65536 B  (C-tile fp32)  -> union = 64 KB exactly
    } sm;

    const int tid = threadIdx.x;
    const int R0  = blockIdx.x * MT;

    // ---- stage A = clamp(concat(raw,edge,time), +-50) as bf16 into LDS ----
    #pragma unroll
    for (int i = 0; i < 16; ++i) {                    // raw: 4096 float4
        int idx = i * 256 + tid;
        int row = idx >> 7, c4 = idx & 127;
        float4 v = ((const float4*)(raw + (size_t)(R0 + row) * DDIM))[c4];
        unsigned int lo = (unsigned)f2bf(clampf(v.x, -50.f, 50.f)) |
                          ((unsigned)f2bf(clampf(v.y, -50.f, 50.f)) << 16);
        unsigned int hi = (unsigned)f2bf(clampf(v.z, -50.f, 50.f)) |
                          ((unsigned)f2bf(clampf(v.w, -50.f, 50.f)) << 16);
        *(uint2*)(&sm.a[row * APAD + c4 * 4]) = make_uint2(lo, hi);
    }
    #pragma unroll
    for (int i = 0; i < 8; ++i) {                     // edge: 2048 float4
        int idx = i * 256 + tid;
        int row = idx >> 6, c4 = idx & 63;
        float4 v = ((const float4*)(edge + (size_t)(R0 + row) * EDIM))[c4];
        unsigned int lo = (unsigned)f2bf(clampf(v.x, -50.f, 50.f)) |
                          ((unsigned)f2bf(clampf(v.y, -50.f, 50.f)) << 16);
        unsigned int hi = (unsigned)f2bf(clampf(v.z, -50.f, 50.f)) |
                          ((unsigned)f2bf(clampf(v.w, -50.f, 50.f)) << 16);
        *(uint2*)(&sm.a[row * APAD + DDIM + c4 * 4]) = make_uint2(lo, hi);
    }
    #pragma unroll
    for (int i = 0; i < 4; ++i) {                     // time: 1024 float4
        int idx = i * 256 + tid;
        int row = idx >> 5, c4 = idx & 31;
        float4 v = ((const float4*)(timee + (size_t)(R0 + row) * TDIM))[c4];
        unsigned int lo = (unsigned)f2bf(clampf(v.x, -50.f, 50.f)) |
                          ((unsigned)f2bf(clampf(v.y, -50.f, 50.f)) << 16);
        unsigned int hi = (unsigned)f2bf(clampf(v.z, -50.f, 50.f)) |
                          ((unsigned)f2bf(clampf(v.w, -50.f, 50.f)) << 16);
        *(uint2*)(&sm.a[row * APAD + DDIM + EDIM + c4 * 4]) = make_uint2(lo, hi);
    }
    __syncthreads();

    // ---- MFMA GEMM: C[32x512] = A[32x896] @ Wq^T ----
    const int w = tid >> 6, l = tid & 63, mlo = l & 15, quad = l >> 4;
    f32x4 acc[2][8];
    #pragma unroll
    for (int rt = 0; rt < 2; ++rt)
        #pragma unroll
        for (int c = 0; c < 8; ++c) { acc[rt][c] = (f32x4){0.f, 0.f, 0.f, 0.f}; }

    const unsigned short* bbase  = wqb + (size_t)(w * 128 + mlo) * KTOT + quad * 8;
    const unsigned short* abase0 = &sm.a[ mlo        * APAD + quad * 8];
    const unsigned short* abase1 = &sm.a[(16 + mlo)  * APAD + quad * 8];

    for (int k0 = 0; k0 < KTOT; k0 += 32) {
        bf16x8 a0 = *(const bf16x8*)(abase0 + k0);
        bf16x8 a1 = *(const bf16x8*)(abase1 + k0);
        #pragma unroll
        for (int c = 0; c < 8; ++c) {
            bf16x8 b = *(const bf16x8*)(bbase + (size_t)c * 16 * KTOT + k0);
            acc[0][c] = __builtin_amdgcn_mfma_f32_16x16x32_bf16(a0, b, acc[0][c], 0, 0, 0);
            acc[1][c] = __builtin_amdgcn_mfma_f32_16x16x32_bf16(a1, b, acc[1][c], 0, 0, 0);
        }
    }

    __syncthreads();   // all waves done reading A before we overwrite the union
    #pragma unroll
    for (int rt = 0; rt < 2; ++rt)
        #pragma unroll
        for (int c = 0; c < 8; ++c)
            #pragma unroll
            for (int r = 0; r < 4; ++r)
                sm.c[(rt * 16 + quad * 4 + r) * DDIM + w * 128 + c * 16 + mlo] = acc[rt][c][r];
    __syncthreads();

    // ---- LN + tanh, wave w handles rows w*8 .. w*8+7; lane -> cols l+64j ----
    float bqv[8], gv[8], bv[8];
    #pragma unroll
    for (int j = 0; j < 8; ++j) {
        int d = l + 64 * j;
        bqv[j] = bq[d]; gv[j] = gamma[d]; bv[j] = beta[d];
    }
    for (int rr = 0; rr < 8; ++rr) {
        int r = w * 8 + rr;
        float v[8], s = 0.f, sq = 0.f;
        #pragma unroll
        for (int j = 0; j < 8; ++j) {
            v[j] = sm.c[r * DDIM + l + 64 * j] + bqv[j];
            s += v[j]; sq += v[j] * v[j];
        }
        s = wred_sum(s); sq = wred_sum(sq);
        float mu  = s * (1.f / 512.f);
        float var = sq * (1.f / 512.f) - mu * mu;
        float rs  = rsqrtf(fmaxf(var, 0.f) + 1e-6f);
        #pragma unroll
        for (int j = 0; j < 8; ++j) {
            float y = (v[j] - mu) * rs * gv[j] + bv[j];
            qout[(size_t)(R0 + r) * DDIM + l + 64 * j] = tanh_fast(y);
        }
    }
}

// ---------------- kernel 2: per-row attention + gate + final LN -------------------
// 1 wave per row; reads query from `out`, overwrites with final result.
__global__ __launch_bounds__(256) void k_attn(
    const float* __restrict__ raw, const float* __restrict__ timee,
    const float* __restrict__ prot, const float* __restrict__ wg,
    const float* __restrict__ bg, const float* __restrict__ gamma,
    const float* __restrict__ beta, const float* __restrict__ temperature,
    float* __restrict__ out)
{
    const int R = blockIdx.x * 4 + (threadIdx.x >> 6);
    const int l = threadIdx.x & 63;
    const size_t rbase = (size_t)R * DDIM;

    float q[8], rw[8], p[5][8], tv[2];
    #pragma unroll
    for (int j = 0; j < 8; ++j) {
        q[j]  = out[rbase + l + 64 * j];
        rw[j] = clampf(raw[rbase + l + 64 * j], -50.f, 50.f);
    }
    tv[0] = timee[(size_t)R * TDIM + l];
    tv[1] = timee[(size_t)R * TDIM + l + 64];
    #pragma unroll
    for (int k = 0; k < 5; ++k)
        #pragma unroll
        for (int j = 0; j < 8; ++j)
            p[k][j] = prot[((size_t)R * 5 + k) * DDIM + l + 64 * j];

    // cosine sim (q_s = clip(q,+-20) is a no-op: |tanh|<1)
    float qs = 0.f;
    #pragma unroll
    for (int j = 0; j < 8; ++j) qs += q[j] * q[j];
    qs = wred_sum(qs);
    float qinv = 1.f / fmaxf(sqrtf(qs), 1e-6f);

    float sim[5];
    #pragma unroll
    for (int k = 0; k < 5; ++k) {
        float d = 0.f, pn = 0.f;
        #pragma unroll
        for (int j = 0; j < 8; ++j) {
            float ps = clampf(p[k][j], -20.f, 20.f);
            d += q[j] * ps; pn += ps * ps;
        }
        d = wred_sum(d); pn = wred_sum(pn);
        sim[k] = d * qinv * (1.f / fmaxf(sqrtf(pn), 1e-6f));
    }
    float temp = clampf(temperature[0], 0.5f, 5.f);
    float tinv = 1.f / (temp + 1e-4f);
    float mx = -1e30f;
    #pragma unroll
    for (int k = 0; k < 5; ++k) { sim[k] = clampf(sim[k], -15.f, 15.f) * tinv; mx = fmaxf(mx, sim[k]); }
    float e[5], Z = 0.f;
    #pragma unroll
    for (int k = 0; k < 5; ++k) { e[k] = __expf(sim[k] - mx); Z += e[k]; }
    float zi = 1.f / Z;
    #pragma unroll
    for (int k = 0; k < 5; ++k) e[k] = clampf(e[k] * zi, 0.f, 1.f);

    float cand[8];
    #pragma unroll
    for (int j = 0; j < 8; ++j) {
        float c = 0.f;
        #pragma unroll
        for (int k = 0; k < 5; ++k) c += e[k] * p[k][j];
        cand[j] = clampf(c, -5.f, 5.f);
    }

    // gate: sigmoid(clip(Wg . clip([raw, cand, time], +-30) + bg, +-10))
    float gp = 0.f;
    #pragma unroll
    for (int j = 0; j < 8; ++j) {
        int d = l + 64 * j;
        gp += wg[d]       * clampf(rw[j],   -30.f, 30.f);
        gp += wg[512 + d] * clampf(cand[j], -30.f, 30.f);
    }
    gp += wg[1024 + l]      * clampf(tv[0], -30.f, 30.f);
    gp += wg[1024 + l + 64] * clampf(tv[1], -30.f, 30.f);
    gp = wred_sum(gp);
    float gl = clampf(gp + bg[0], -10.f, 10.f);
    float g  = 1.f / (1.f + __expf(-gl));

    float u[8], s = 0.f, sq = 0.f;
    #pragma unroll
    for (int j = 0; j < 8; ++j) {
        float gated = (1.f - g) * rw[j] + g * cand[j];
        u[j] = 0.8f * rw[j] + 0.2f * gated;
        s += u[j]; sq += u[j] * u[j];
    }
    s = wred_sum(s); sq = wred_sum(sq);
    float mu  = s * (1.f / 512.f);
    float var = sq * (1.f / 512.f) - mu * mu;
    float rs  = rsqrtf(fmaxf(var, 0.f) + 1e-6f);
    #pragma unroll
    for (int j = 0; j < 8; ++j) {
        int d = l + 64 * j;
        float y = (u[j] - mu) * rs * gamma[d] + beta[d];
        out[rbase + d] = clampf(y, -10.f, 10.f);
    }
}

extern "C" void kernel_launch(void* const* d_in, const int* in_sizes, int n_in,
                              void* d_out, int out_size, void* d_ws, size_t ws_size,
                              hipStream_t stream) {
    const float* raw   = (const float*)d_in[0];
    // d_in[1] = node_features: unused by the reference
    const float* edge  = (const float*)d_in[2];
    const float* tim   = (const float*)d_in[3];
    const float* prot  = (const float*)d_in[4];
    const float* Wq    = (const float*)d_in[5];
    const float* bq    = (const float*)d_in[6];
    const float* Wg    = (const float*)d_in[7];
    const float* bg    = (const float*)d_in[8];
    const float* gamma = (const float*)d_in[9];
    const float* beta  = (const float*)d_in[10];
    const float* temp  = (const float*)d_in[11];
    float* out = (float*)d_out;
    unsigned short* wqb = (unsigned short*)d_ws;   // 458752 bf16 = 0.9 MB

    k_conv_wq<<<448, 256, 0, stream>>>(Wq, wqb);                 // 448*256 == 114688 float4
    k_qproj<<<NROWS / MT, 256, 0, stream>>>(raw, edge, tim, wqb, bq, gamma, beta, out);
    k_attn <<<NROWS / 4, 256, 0, stream>>>(raw, tim, prot, Wg, bg, gamma, beta, temp, out);
}